// Round 12
// baseline (311.152 us; speedup 1.0000x reference)
//
#include <hip/hip_runtime.h>
#include <hip/hip_bf16.h>
#include <stdint.h>

typedef int i32x4 __attribute__((ext_vector_type(4)));

constexpr int IN_F = 1024;
constexpr int OUT_F = 1024;
constexpr int M_TOT = 8 * 4096;   // 32768 tokens
constexpr int K_TOT = 1024;
constexpr int N_TOT = 1024;

// ---------------- kernel 1: unpack ternary weights (bit-plane permuted) -> int8 ----------------
__global__ __launch_bounds__(256) void unpack_kernel(
    const int* __restrict__ packed,
    int8_t* __restrict__ wt)           // [OUT_F][IN_F] int8 in {-1,0,1} (B^T layout)
{
    const int o = blockIdx.x;
    const int k0 = threadIdx.x * 4;
    const int sh = (o >> 8) * 2;
    const int pbase = ((o & 255) << 10) + k0;
    const int4 pw = *reinterpret_cast<const int4*>(packed + pbase);
    char4 r;
    r.x = (char)(((pw.x >> sh) & 3) - 1);
    r.y = (char)(((pw.y >> sh) & 3) - 1);
    r.z = (char)(((pw.z >> sh) & 3) - 1);
    r.w = (char)(((pw.w >> sh) & 3) - 1);
    *reinterpret_cast<char4*>(wt + (size_t)o * IN_F + k0) = r;
}

// ---------------- kernel 2: FUSED quant + int8 MFMA GEMM (r5 core) ----------------
// Each block (tm,tn) first quantizes rows [tm*256+tn*64, +64) of x -> q (no dup:
// aggregate x read = 128 MiB exactly), writes inv_row, fence, atomicAdd(cnt[tm]).
// Spins until cnt[tm]==4 (siblings share the dispatch round under the XCD remap);
// BOUNDED spin: on timeout, self-quantizes the other 192 rows (byte-identical
// values -> benign race) and proceeds -> correct under ANY dispatch order.
// GEMM phase: r5-verbatim 256x256 BK=128, 2-phase, dbuf, involution swizzle,
// counted vmcnt(4)/vmcnt(2); epilogue uses nontemporal C stores.
constexpr int BM = 256, BN = 256, BK = 128;
constexpr int NT = K_TOT / BK;   // 8

__global__ __launch_bounds__(512, 2) void fused_kernel(
    const float* __restrict__ x,
    const int8_t* __restrict__ wb,     // unpacked ternary (B^T), L2-resident
    const float* __restrict__ wscale,
    const float* __restrict__ bias,
    int8_t* __restrict__ q,            // [M_TOT][K_TOT] int8 (workspace)
    float* __restrict__ inv_row,       // [M_TOT] (workspace)
    int* __restrict__ cnt,             // [128] zeroed each launch
    float* __restrict__ out)
{
    // XCD-aware swizzle: nwg = 512 -> bijective remap; siblings (tm, 0..3) map to
    // 4 consecutive remapped bids -> same XCD chunk, same dispatch round.
    int bid = blockIdx.x;
    bid = (bid & 7) * ((int)gridDim.x >> 3) + (bid >> 3);
    const int tm = bid >> 2;            // 0..127
    const int tn = bid & 3;             // 0..3

    const int tid = threadIdx.x;
    const int lane = tid & 63;
    const int wid = tid >> 6;           // 0..7
    const int wr = wid >> 2;            // 0..1 (M half)
    const int wc = wid & 3;             // 0..3 (N quarter)

    __shared__ int8_t lds[2][2][2][128 * 128];  // [buf][ab][region] = 128 KiB
    __shared__ int sready;

    // ======== phase 1: quantize own 64-row slice ========
    const float wsc = wscale[0];
    const int c8 = lane & 7;            // lane-in-row (8 lanes per row)
    auto quant_rows = [&](int rows0) {
        const int r = rows0 + wid * 8 + (lane >> 3);
        const float4* xr = reinterpret_cast<const float4*>(x + (size_t)r * IN_F);
        // pass 1: row max (coalesced: 8 lanes x 16B = 128 B per row per instr)
        float m = 0.f;
        #pragma unroll
        for (int j = 0; j < 8; ++j) {
            #pragma unroll
            for (int u = 0; u < 4; ++u) {
                const float4 v = xr[4 * c8 + 32 * j + u];
                m = fmaxf(m, fmaxf(fmaxf(fabsf(v.x), fabsf(v.y)),
                                   fmaxf(fabsf(v.z), fabsf(v.w))));
            }
        }
        m = fmaxf(m, __shfl_xor(m, 1));
        m = fmaxf(m, __shfl_xor(m, 2));
        m = fmaxf(m, __shfl_xor(m, 4));
        const float a = fmaxf(m, 1e-5f);
        const float as = 127.0f / a;
        if (c8 == 0) inv_row[r] = (a / 127.0f) * wsc;
        // pass 2: re-read (L2-hot) and quantize; 16B i8 store per lane per j
        #pragma unroll
        for (int j = 0; j < 8; ++j) {
            int4 o4;
            int* op = &o4.x;
            #pragma unroll
            for (int u = 0; u < 4; ++u) {
                const float4 v = xr[4 * c8 + 32 * j + u];
                const int b0 = (int)fminf(fmaxf(rintf(v.x * as), -128.f), 127.f) & 255;
                const int b1 = (int)fminf(fmaxf(rintf(v.y * as), -128.f), 127.f) & 255;
                const int b2 = (int)fminf(fmaxf(rintf(v.z * as), -128.f), 127.f) & 255;
                const int b3 = (int)fminf(fmaxf(rintf(v.w * as), -128.f), 127.f) & 255;
                op[u] = b0 | (b1 << 8) | (b2 << 16) | (b3 << 24);
            }
            reinterpret_cast<int4*>(q + (size_t)r * K_TOT)[c8 + 8 * j] = o4;
        }
    };

    quant_rows(tm * 256 + tn * 64);
    __threadfence();                    // release own slice
    __syncthreads();
    if (tid == 0) {
        atomicAdd(cnt + tm, 1);
        int it = 0;
        while (atomicAdd(cnt + tm, 0) < 4 && it < 20000) {
            __builtin_amdgcn_s_sleep(8);
            ++it;
        }
        sready = (it < 20000) ? 1 : 0;
    }
    __syncthreads();
    if (!sready) {
        // timeout fallback: self-quantize the other 192 rows (identical values)
        #pragma unroll 1
        for (int t2 = 1; t2 < 4; ++t2)
            quant_rows(tm * 256 + ((tn + t2) & 3) * 64);
        __threadfence();
    }
    __syncthreads();
    __threadfence();                    // acquire side

    // ======== phase 2: GEMM (r5 verbatim) ========
    const int rowA0 = tm * BM;
    const int rowB0 = tn * BN;
    const int frow = lane & 15;
    const int fq = lane >> 4;

    i32x4 acc[8][4] = {};

    auto stage = [&](int buf, int ab, int region, int kt) {
        const int8_t* base = ab ? wb : q;
        #pragma unroll
        for (int j = 0; j < 2; ++j) {
            const int c = j * 512 + tid;
            const int rl = c >> 3, cc = c & 7;
            const int grow = ab ? (rowB0 + region * 128 + rl)
                                : (rowA0 + (rl & 64) * 2 + region * 64 + (rl & 63));
            const int scc = cc ^ (rl & 7);
            const int8_t* src = base + (size_t)grow * K_TOT + kt * BK + scc * 16;
            __builtin_amdgcn_global_load_lds(
                (const __attribute__((address_space(1))) void*)src,
                (__attribute__((address_space(3))) void*)&lds[buf][ab][region][c * 16],
                16, 0, 0);
        }
    };

    auto ldA = [&](int buf, int region, int mf, int ks) -> i32x4 {
        const int local = wr * 64 + (mf & 3) * 16 + frow;
        const int ch = (ks * 4 + fq) ^ (local & 7);
        return *reinterpret_cast<const i32x4*>(&lds[buf][0][region][local * 128 + ch * 16]);
    };
    auto ldB = [&](int buf, int nf, int ks) -> i32x4 {
        const int region = wc >> 1;
        const int local = (wc & 1) * 64 + nf * 16 + frow;
        const int ch = (ks * 4 + fq) ^ (local & 7);
        return *reinterpret_cast<const i32x4*>(&lds[buf][1][region][local * 128 + ch * 16]);
    };

    stage(0, 1, 0, 0); stage(0, 1, 1, 0); stage(0, 0, 0, 0); stage(0, 0, 1, 0);
    asm volatile("s_waitcnt vmcnt(0)" ::: "memory");
    __builtin_amdgcn_s_barrier();

    for (int T = 0; T < NT; ++T) {
        const int cur = T & 1, nxt = cur ^ 1;
        const bool st = (T + 1 < NT);
        i32x4 aF[4][2], bF[4][2];

        // ---- Ph0: read A-R0 (8) + B-all (8); stage nxt B; MFMA rows-lo (32)
        #pragma unroll
        for (int mf = 0; mf < 4; ++mf)
            #pragma unroll
            for (int ks = 0; ks < 2; ++ks)
                aF[mf][ks] = ldA(cur, 0, mf, ks);
        #pragma unroll
        for (int nf = 0; nf < 4; ++nf)
            #pragma unroll
            for (int ks = 0; ks < 2; ++ks)
                bF[nf][ks] = ldB(cur, nf, ks);
        if (st) { stage(nxt, 1, 0, T + 1); stage(nxt, 1, 1, T + 1); }
        __builtin_amdgcn_s_barrier();
        asm volatile("s_waitcnt lgkmcnt(0)" ::: "memory");
        __builtin_amdgcn_sched_barrier(0);
        __builtin_amdgcn_s_setprio(1);
        #pragma unroll
        for (int mf = 0; mf < 4; ++mf)
            #pragma unroll
            for (int nf = 0; nf < 4; ++nf)
                #pragma unroll
                for (int ks = 0; ks < 2; ++ks)
                    acc[mf][nf] = __builtin_amdgcn_mfma_i32_16x16x64_i8(
                        aF[mf][ks], bF[nf][ks], acc[mf][nf], 0, 0, 0);
        __builtin_amdgcn_s_setprio(0);
        if (st) asm volatile("s_waitcnt vmcnt(4)" ::: "memory");
        else    asm volatile("s_waitcnt vmcnt(0)" ::: "memory");
        __builtin_amdgcn_s_barrier();

        // ---- Ph1: read A-R1 (8); stage nxt A; MFMA rows-hi (32)
        #pragma unroll
        for (int mf = 0; mf < 4; ++mf)
            #pragma unroll
            for (int ks = 0; ks < 2; ++ks)
                aF[mf][ks] = ldA(cur, 1, mf, ks);
        if (st) { stage(nxt, 0, 0, T + 1); stage(nxt, 0, 1, T + 1); }
        __builtin_amdgcn_s_barrier();
        asm volatile("s_waitcnt lgkmcnt(0)" ::: "memory");
        __builtin_amdgcn_sched_barrier(0);
        __builtin_amdgcn_s_setprio(1);
        #pragma unroll
        for (int mf = 0; mf < 4; ++mf)
            #pragma unroll
            for (int nf = 0; nf < 4; ++nf)
                #pragma unroll
                for (int ks = 0; ks < 2; ++ks)
                    acc[4 + mf][nf] = __builtin_amdgcn_mfma_i32_16x16x64_i8(
                        aF[mf][ks], bF[nf][ks], acc[4 + mf][nf], 0, 0, 0);
        __builtin_amdgcn_s_setprio(0);
        asm volatile("s_waitcnt vmcnt(2)" ::: "memory");
        __builtin_amdgcn_s_barrier();
    }

    // epilogue: C/D 16x16 layout: col = lane&15, row = fq*4 + reg; NT stores.
    #pragma unroll
    for (int mi = 0; mi < 8; ++mi) {
        #pragma unroll
        for (int j = 0; j < 4; ++j) {
            const int gm = rowA0 + wr * 128 + mi * 16 + fq * 4 + j;
            const float sc = inv_row[gm];
            #pragma unroll
            for (int nf = 0; nf < 4; ++nf) {
                const int gn = rowB0 + wc * 64 + nf * 16 + frow;
                __builtin_nontemporal_store(
                    (float)acc[mi][nf][j] * sc + bias[gn],
                    &out[(size_t)gm * N_TOT + gn]);
            }
        }
    }
}

extern "C" void kernel_launch(void* const* d_in, const int* in_sizes, int n_in,
                              void* d_out, int out_size, void* d_ws, size_t ws_size,
                              hipStream_t stream) {
    const float* x = (const float*)d_in[0];
    const int* packed = (const int*)d_in[1];
    const float* wscale = (const float*)d_in[2];
    const float* bias = (const float*)d_in[3];
    float* out = (float*)d_out;

    int8_t* q = (int8_t*)d_ws;                                          // 32 MiB
    int8_t* wt = (int8_t*)((char*)d_ws + (size_t)M_TOT * K_TOT);        // 1 MiB
    float* inv_row = (float*)((char*)d_ws + (size_t)M_TOT * K_TOT + (size_t)N_TOT * K_TOT);
    int* cnt = (int*)((char*)d_ws + (size_t)M_TOT * K_TOT + (size_t)N_TOT * K_TOT
                      + (size_t)M_TOT * sizeof(float));

    hipMemsetAsync(cnt, 0, 128 * sizeof(int), stream);   // flags zeroed every launch
    unpack_kernel<<<OUT_F, 256, 0, stream>>>(packed, wt);
    fused_kernel<<<(M_TOT / BM) * (N_TOT / BN), 512, 0, stream>>>(
        x, wt, wscale, bias, q, inv_row, cnt, out);
}

// Round 13
// 86.241 us; speedup vs baseline: 3.6079x; 3.6079x over previous
//
#include <hip/hip_runtime.h>
#include <hip/hip_bf16.h>
#include <stdint.h>

typedef int i32x4 __attribute__((ext_vector_type(4)));

constexpr int IN_F = 1024;
constexpr int OUT_F = 1024;
constexpr int M_TOT = 8 * 4096;   // 32768 tokens
constexpr int K_TOT = 1024;
constexpr int N_TOT = 1024;

// ---------------- kernel 1: per-token int8 fake-quant (+ fused weight unpack) ----------------
__global__ __launch_bounds__(256) void quant_kernel(
    const float* __restrict__ x,
    const float* __restrict__ wscale,
    const int* __restrict__ packed,
    int8_t* __restrict__ q,            // [M_TOT][K_TOT] int8
    float* __restrict__ inv_row,       // [M_TOT]
    int8_t* __restrict__ wt)           // [OUT_F][IN_F] ternary int8 (B^T)
{
    const int row = blockIdx.x;
    const int t = threadIdx.x;
    const float4 v = reinterpret_cast<const float4*>(x + (size_t)row * IN_F)[t];
    float m = fmaxf(fmaxf(fabsf(v.x), fabsf(v.y)), fmaxf(fabsf(v.z), fabsf(v.w)));
    #pragma unroll
    for (int off = 32; off > 0; off >>= 1)
        m = fmaxf(m, __shfl_xor(m, off));
    __shared__ float smax[4];
    if ((t & 63) == 0) smax[t >> 6] = m;
    __syncthreads();
    m = fmaxf(fmaxf(smax[0], smax[1]), fmaxf(smax[2], smax[3]));
    const float a = fmaxf(m, 1e-5f);
    const float as = 127.0f / a;

    char4 o;
    o.x = (char)(int)fminf(fmaxf(rintf(v.x * as), -128.0f), 127.0f);
    o.y = (char)(int)fminf(fmaxf(rintf(v.y * as), -128.0f), 127.0f);
    o.z = (char)(int)fminf(fmaxf(rintf(v.z * as), -128.0f), 127.0f);
    o.w = (char)(int)fminf(fmaxf(rintf(v.w * as), -128.0f), 127.0f);
    reinterpret_cast<char4*>(q + (size_t)row * IN_F)[t] = o;
    if (t == 0) inv_row[row] = (a / 127.0f) * wscale[0];

    // fused unpack: blocks 0..1023 also expand one weight row (r5-verified mapping)
    if (row < OUT_F) {
        const int oo = row;
        const int k0 = t * 4;
        const int sh = (oo >> 8) * 2;
        const int pbase = ((oo & 255) << 10) + k0;
        const int4 pw = *reinterpret_cast<const int4*>(packed + pbase);
        char4 r;
        r.x = (char)(((pw.x >> sh) & 3) - 1);
        r.y = (char)(((pw.y >> sh) & 3) - 1);
        r.z = (char)(((pw.z >> sh) & 3) - 1);
        r.w = (char)(((pw.w >> sh) & 3) - 1);
        *reinterpret_cast<char4*>(wt + (size_t)oo * IN_F + k0) = r;
    }
}

// ---------------- kernel 2: int8 MFMA GEMM, r5 core + software-pipelined lgkm ----------------
// 256x256, BK=128, 8 waves (2M x 4N), 128x64/wave, dbuf, involution swizzle (0-conflict).
// NEW vs r5: frag reads pipelined with counted lgkmcnt instead of full drains.
// Steady-state invariant entering tile T: Ph0 frags (A-R0 + B, 16 ds_read) already in
// flight (issued after the end-of-(T-1) barrier, data vmcnt-certified by ALL waves).
// Tile T: issue Ph1 reads (8) + stage T+1 (8 vm) -> lgkmcnt(8) certifies Ph0 (in-order
// DS retirement) -> 32 MFMA -> lgkmcnt(0) certifies Ph1 (hidden under Ph0 MFMA) ->
// 32 MFMA -> vmcnt(0) (T+1 stages, issued ~2 bursts ago: no stall) -> barrier ->
// pre-read Ph0(T+1). Staging T+1 overwrites slot(T-1): last read before end-of-(T-1)
// barrier -> safe. One barrier per tile.
constexpr int BM = 256, BN = 256, BK = 128;
constexpr int NT = K_TOT / BK;   // 8

__global__ __launch_bounds__(512, 2) void gemm_kernel(
    const int8_t* __restrict__ qa,     // [M_TOT][K_TOT] int8
    const int8_t* __restrict__ wb,     // [N_TOT][K_TOT] int8
    const float* __restrict__ inv_row,
    const float* __restrict__ bias,
    float* __restrict__ out)
{
    // XCD-aware swizzle: nwg = 512, divisible by 8 -> bijective simple remap
    int bid = blockIdx.x;
    bid = (bid & 7) * ((int)gridDim.x >> 3) + (bid >> 3);
    const int tm = bid >> 2;            // 0..127
    const int tn = bid & 3;             // 0..3

    const int tid = threadIdx.x;
    const int lane = tid & 63;
    const int wid = tid >> 6;           // 0..7
    const int wr = wid >> 2;            // 0..1 (M half)
    const int wc = wid & 3;             // 0..3 (N quarter)

    __shared__ int8_t lds[2][2][2][128 * 128];  // [buf][ab][region] = 128 KiB

    const int rowA0 = tm * BM;
    const int rowB0 = tn * BN;
    const int frow = lane & 15;
    const int fq = lane >> 4;

    i32x4 acc[8][4] = {};

    auto stage = [&](int buf, int ab, int region, int kt) {
        const int8_t* base = ab ? wb : qa;
        #pragma unroll
        for (int j = 0; j < 2; ++j) {
            const int c = j * 512 + tid;
            const int rl = c >> 3, cc = c & 7;
            const int grow = ab ? (rowB0 + region * 128 + rl)
                                : (rowA0 + (rl & 64) * 2 + region * 64 + (rl & 63));
            const int scc = cc ^ (rl & 7);
            const int8_t* src = base + (size_t)grow * K_TOT + kt * BK + scc * 16;
            __builtin_amdgcn_global_load_lds(
                (const __attribute__((address_space(1))) void*)src,
                (__attribute__((address_space(3))) void*)&lds[buf][ab][region][c * 16],
                16, 0, 0);
        }
    };

    auto ldA = [&](int buf, int region, int mf, int ks) -> i32x4 {
        const int local = wr * 64 + (mf & 3) * 16 + frow;
        const int ch = (ks * 4 + fq) ^ (local & 7);
        return *reinterpret_cast<const i32x4*>(&lds[buf][0][region][local * 128 + ch * 16]);
    };
    auto ldB = [&](int buf, int nf, int ks) -> i32x4 {
        const int region = wc >> 1;
        const int local = (wc & 1) * 64 + nf * 16 + frow;
        const int ch = (ks * 4 + fq) ^ (local & 7);
        return *reinterpret_cast<const i32x4*>(&lds[buf][1][region][local * 128 + ch * 16]);
    };

    i32x4 aF[4][2], bF[4][2], aG[4][2];

    // prologue: stage tile0 (B then A), certify, barrier, pre-read Ph0(0)
    stage(0, 1, 0, 0); stage(0, 1, 1, 0); stage(0, 0, 0, 0); stage(0, 0, 1, 0);
    asm volatile("s_waitcnt vmcnt(0)" ::: "memory");
    __builtin_amdgcn_s_barrier();
    #pragma unroll
    for (int mf = 0; mf < 4; ++mf)
        #pragma unroll
        for (int ks = 0; ks < 2; ++ks)
            aF[mf][ks] = ldA(0, 0, mf, ks);
    #pragma unroll
    for (int nf = 0; nf < 4; ++nf)
        #pragma unroll
        for (int ks = 0; ks < 2; ++ks)
            bF[nf][ks] = ldB(0, nf, ks);
    // 16 ds_reads outstanding entering the loop

    #pragma unroll 1
    for (int T = 0; T < NT; ++T) {
        const int cur = T & 1, nxt = cur ^ 1;
        const bool st = (T + 1 < NT);

        // issue Ph1 reads (A-R1 -> aG) and all of tile T+1's staging
        #pragma unroll
        for (int mf = 0; mf < 4; ++mf)
            #pragma unroll
            for (int ks = 0; ks < 2; ++ks)
                aG[mf][ks] = ldA(cur, 1, mf, ks);
        if (st) {
            stage(nxt, 1, 0, T + 1); stage(nxt, 1, 1, T + 1);
            stage(nxt, 0, 0, T + 1); stage(nxt, 0, 1, T + 1);
        }

        asm volatile("s_waitcnt lgkmcnt(8)" ::: "memory");   // Ph0 frags certified
        __builtin_amdgcn_sched_barrier(0);
        __builtin_amdgcn_s_setprio(1);
        #pragma unroll
        for (int mf = 0; mf < 4; ++mf)
            #pragma unroll
            for (int nf = 0; nf < 4; ++nf)
                #pragma unroll
                for (int ks = 0; ks < 2; ++ks)
                    acc[mf][nf] = __builtin_amdgcn_mfma_i32_16x16x64_i8(
                        aF[mf][ks], bF[nf][ks], acc[mf][nf], 0, 0, 0);
        __builtin_amdgcn_s_setprio(0);

        asm volatile("s_waitcnt lgkmcnt(0)" ::: "memory");   // Ph1 frags (hidden under Ph0)
        __builtin_amdgcn_sched_barrier(0);
        __builtin_amdgcn_s_setprio(1);
        #pragma unroll
        for (int mf = 0; mf < 4; ++mf)
            #pragma unroll
            for (int nf = 0; nf < 4; ++nf)
                #pragma unroll
                for (int ks = 0; ks < 2; ++ks)
                    acc[4 + mf][nf] = __builtin_amdgcn_mfma_i32_16x16x64_i8(
                        aG[mf][ks], bF[nf][ks], acc[4 + mf][nf], 0, 0, 0);
        __builtin_amdgcn_s_setprio(0);

        if (st) {
            asm volatile("s_waitcnt vmcnt(0)" ::: "memory"); // my T+1 stages landed (old)
            __builtin_amdgcn_s_barrier();                    // everyone's landed; T-reads done
            // pre-read Ph0(T+1): A-R0 + B (B(T) dead after Ph1 mfma above)
            #pragma unroll
            for (int mf = 0; mf < 4; ++mf)
                #pragma unroll
                for (int ks = 0; ks < 2; ++ks)
                    aF[mf][ks] = ldA(nxt, 0, mf, ks);
            #pragma unroll
            for (int nf = 0; nf < 4; ++nf)
                #pragma unroll
                for (int ks = 0; ks < 2; ++ks)
                    bF[nf][ks] = ldB(nxt, nf, ks);
        }
    }

    // epilogue: C/D 16x16 layout: col = lane&15, row = fq*4 + reg; nontemporal stores.
    #pragma unroll
    for (int mi = 0; mi < 8; ++mi) {
        #pragma unroll
        for (int j = 0; j < 4; ++j) {
            const int gm = rowA0 + wr * 128 + mi * 16 + fq * 4 + j;
            const float sc = inv_row[gm];
            #pragma unroll
            for (int nf = 0; nf < 4; ++nf) {
                const int gn = rowB0 + wc * 64 + nf * 16 + frow;
                __builtin_nontemporal_store(
                    (float)acc[mi][nf][j] * sc + bias[gn],
                    &out[(size_t)gm * N_TOT + gn]);
            }
        }
    }
}

extern "C" void kernel_launch(void* const* d_in, const int* in_sizes, int n_in,
                              void* d_out, int out_size, void* d_ws, size_t ws_size,
                              hipStream_t stream) {
    const float* x = (const float*)d_in[0];
    const int* packed = (const int*)d_in[1];
    const float* wscale = (const float*)d_in[2];
    const float* bias = (const float*)d_in[3];
    float* out = (float*)d_out;

    int8_t* q = (int8_t*)d_ws;                                          // 32 MiB
    int8_t* wt = (int8_t*)((char*)d_ws + (size_t)M_TOT * K_TOT);        // 1 MiB
    float* inv_row = (float*)((char*)d_ws + (size_t)M_TOT * K_TOT + (size_t)N_TOT * K_TOT);

    quant_kernel<<<M_TOT, 256, 0, stream>>>(x, wscale, packed, q, inv_row, wt);
    gemm_kernel<<<(M_TOT / BM) * (N_TOT / BN), 512, 0, stream>>>(q, wt, inv_row, bias, out);
}